// Round 1
// baseline (11698.000 us; speedup 1.0000x reference)
//
#include <hip/hip_runtime.h>
#include <math.h>

// Problem constants (B=2, S=2048, D_MODEL=1024, H=16, DK=64)
#define MDIM 4096   // B*S rows
#define NDIM 1024
#define KDIM 1024
#define S_LEN 2048
#define NH 16
#define DK 64

// ---------------------------------------------------------------------------
// GEMM NT: Y = A(M,K) @ W(N,K)^T + bias(N)
// 64x64 output tile per block, 256 threads, 4x4 per thread, K-step 16.
// split_head=1: write Y[m][n] -> q[(b*NH+h)*S_LEN + s][d]  (b=m/S, s=m%S, h=n/64, d=n%64)
// ---------------------------------------------------------------------------
__global__ __launch_bounds__(256)
void gemm_nt_kernel(const float* __restrict__ A, const float* __restrict__ W,
                    const float* __restrict__ bias, float* __restrict__ Y,
                    int split_head)
{
    __shared__ float As[16][68];   // [k][m], pad 68 keeps 16B alignment per row
    __shared__ float Ws[16][68];   // [k][n]
    const int tid = threadIdx.x;
    const int m0 = blockIdx.y << 6;
    const int n0 = blockIdx.x << 6;
    const int tx = tid & 15;
    const int ty = tid >> 4;

    float acc[4][4] = {};

    for (int k0 = 0; k0 < KDIM; k0 += 16) {
        #pragma unroll
        for (int i = 0; i < 4; i++) {
            int e = tid + (i << 8);
            int r = e >> 4;     // 0..63
            int c = e & 15;     // 0..15
            As[c][r] = A[(m0 + r) * KDIM + k0 + c];
            Ws[c][r] = W[(n0 + r) * KDIM + k0 + c];
        }
        __syncthreads();
        #pragma unroll
        for (int kk = 0; kk < 16; kk++) {
            float a[4], w[4];
            #pragma unroll
            for (int i = 0; i < 4; i++) a[i] = As[kk][ty * 4 + i];
            #pragma unroll
            for (int j = 0; j < 4; j++) w[j] = Ws[kk][tx * 4 + j];
            #pragma unroll
            for (int i = 0; i < 4; i++)
                #pragma unroll
                for (int j = 0; j < 4; j++)
                    acc[i][j] += a[i] * w[j];
        }
        __syncthreads();
    }

    #pragma unroll
    for (int i = 0; i < 4; i++) {
        int m = m0 + ty * 4 + i;
        #pragma unroll
        for (int j = 0; j < 4; j++) {
            int n = n0 + tx * 4 + j;
            float val = acc[i][j] + bias[n];
            if (split_head) {
                int b = m >> 11, s = m & (S_LEN - 1);
                int h = n >> 6,  d = n & (DK - 1);
                Y[(((size_t)(b * NH + h) * S_LEN + s) << 6) + d] = val;
            } else {
                Y[(size_t)m * NDIM + n] = val;
            }
        }
    }
}

// ---------------------------------------------------------------------------
// Fused attention: per block = (b, h, 16-row q tile).
// 256 threads: thread = (row r = tid/16, key-stripe lane16 = tid%16).
// Pass 1: online (max, sumexp) over keys lane16+16j; shuffle-combine 16 lanes.
// Pass 2: recompute score, write attn = exp(s-m)/l, accumulate ctx += p*v.
// ctx written in (B, S, H, DK) == (B, S, D_MODEL) layout for the out-proj GEMM.
// ---------------------------------------------------------------------------
__global__ __launch_bounds__(256)
void attn_kernel(const float* __restrict__ q, const float* __restrict__ k,
                 const float* __restrict__ v, const int* __restrict__ mask,
                 float* __restrict__ attn, float* __restrict__ ctx)
{
    const int b = blockIdx.z;
    const int h = blockIdx.y;
    const int q0 = blockIdx.x << 4;
    const int tid = threadIdx.x;
    const int r = tid >> 4;
    const int lane16 = tid & 15;

    const float* qrow  = q + (((size_t)(b * NH + h) * S_LEN + q0 + r) << 6);
    const float* kbase = k + (((size_t)(b * NH + h) * S_LEN) << 6);
    const float* vbase = v + (((size_t)(b * NH + h) * S_LEN) << 6);
    const int*   mrow  = mask + b * S_LEN;

    // q row in registers (64 floats)
    float4 qreg[16];
    #pragma unroll
    for (int d4 = 0; d4 < 16; d4++) qreg[d4] = ((const float4*)qrow)[d4];

    const float scale = 0.125f;   // 1/sqrt(64)

    // ---- pass 1: online softmax stats over this thread's key stripe ----
    float m = -1e30f, l = 0.f;
    for (int j = 0; j < 128; j++) {
        int kk = lane16 + (j << 4);
        const float4* krow = (const float4*)(kbase + ((size_t)kk << 6));
        float s = 0.f;
        #pragma unroll
        for (int d4 = 0; d4 < 16; d4++) {
            float4 kv = krow[d4];
            s += qreg[d4].x * kv.x + qreg[d4].y * kv.y +
                 qreg[d4].z * kv.z + qreg[d4].w * kv.w;
        }
        s *= scale;
        if (mrow[kk] == 0) s = -1e9f;
        float mn = fmaxf(m, s);
        l = l * __expf(m - mn) + __expf(s - mn);
        m = mn;
    }
    // combine the 16 stripes of this row (contiguous lanes within a wave)
    #pragma unroll
    for (int off = 1; off < 16; off <<= 1) {
        float m2 = __shfl_xor(m, off);
        float l2 = __shfl_xor(l, off);
        float mn = fmaxf(m, m2);
        l = l * __expf(m - mn) + l2 * __expf(m2 - mn);
        m = mn;
    }
    float inv_l = 1.0f / l;

    // ---- pass 2: write attn, accumulate ctx ----
    float acc[64];
    #pragma unroll
    for (int d = 0; d < 64; d++) acc[d] = 0.f;
    float* arow = attn + ((size_t)(b * NH + h) * S_LEN + q0 + r) * S_LEN;

    for (int j = 0; j < 128; j++) {
        int kk = lane16 + (j << 4);
        const float4* krow = (const float4*)(kbase + ((size_t)kk << 6));
        float s = 0.f;
        #pragma unroll
        for (int d4 = 0; d4 < 16; d4++) {
            float4 kv = krow[d4];
            s += qreg[d4].x * kv.x + qreg[d4].y * kv.y +
                 qreg[d4].z * kv.z + qreg[d4].w * kv.w;
        }
        s *= scale;
        if (mrow[kk] == 0) s = -1e9f;
        float p = __expf(s - m) * inv_l;
        arow[kk] = p;

        const float4* vrow = (const float4*)(vbase + ((size_t)kk << 6));
        #pragma unroll
        for (int d4 = 0; d4 < 16; d4++) {
            float4 vv = vrow[d4];
            acc[d4 * 4 + 0] += p * vv.x;
            acc[d4 * 4 + 1] += p * vv.y;
            acc[d4 * 4 + 2] += p * vv.z;
            acc[d4 * 4 + 3] += p * vv.w;
        }
    }

    // reduce ctx across the 16 stripes of each row
    #pragma unroll
    for (int off = 1; off < 16; off <<= 1) {
        #pragma unroll
        for (int d = 0; d < 64; d++)
            acc[d] += __shfl_xor(acc[d], off);
    }

    __shared__ float ctxs[16][64];
    if (lane16 == 0) {
        #pragma unroll
        for (int d = 0; d < 64; d++) ctxs[r][d] = acc[d];
    }
    __syncthreads();

    // cooperative coalesced write, (B, S, H, DK) layout
    {
        int rr = tid >> 4;
        int d4 = tid & 15;
        float4 val = ((const float4*)&ctxs[rr][0])[d4];
        float* dst = ctx + (((size_t)(b * S_LEN + q0 + rr) * NH + h) << 6) + (d4 << 2);
        *(float4*)dst = val;
    }
}

// ---------------------------------------------------------------------------
extern "C" void kernel_launch(void* const* d_in, const int* in_sizes, int n_in,
                              void* d_out, int out_size, void* d_ws, size_t ws_size,
                              hipStream_t stream)
{
    const float* query = (const float*)d_in[0];
    const float* key   = (const float*)d_in[1];
    const float* value = (const float*)d_in[2];
    const int*   mask  = (const int*)d_in[3];
    const float* w_q = (const float*)d_in[4];
    const float* b_q = (const float*)d_in[5];
    const float* w_k = (const float*)d_in[6];
    const float* b_k = (const float*)d_in[7];
    const float* w_v = (const float*)d_in[8];
    const float* b_v = (const float*)d_in[9];
    const float* w_o = (const float*)d_in[10];
    const float* b_o = (const float*)d_in[11];

    float* out  = (float*)d_out;                       // (B,S,D_MODEL) = 4,194,304 floats
    float* attn = (float*)d_out + (size_t)4194304;     // (B,H,S,S)

    float* qws  = (float*)d_ws;                        // (B,H,S,DK) 16 MB
    float* kws  = qws + 4194304;
    float* vws  = kws + 4194304;
    float* ctxw = vws + 4194304;                       // (B,S,D_MODEL) 16 MB

    dim3 gemm_grid(NDIM / 64, MDIM / 64);   // (16, 64)
    dim3 block(256);

    hipLaunchKernelGGL(gemm_nt_kernel, gemm_grid, block, 0, stream, query, w_q, b_q, qws, 1);
    hipLaunchKernelGGL(gemm_nt_kernel, gemm_grid, block, 0, stream, key,   w_k, b_k, kws, 1);
    hipLaunchKernelGGL(gemm_nt_kernel, gemm_grid, block, 0, stream, value, w_v, b_v, vws, 1);

    dim3 attn_grid(S_LEN / 16, NH, 2);      // (128, 16, 2)
    hipLaunchKernelGGL(attn_kernel, attn_grid, block, 0, stream, qws, kws, vws, mask, attn, ctxw);

    hipLaunchKernelGGL(gemm_nt_kernel, gemm_grid, block, 0, stream, ctxw, w_o, b_o, out, 0);
}